// Round 7
// baseline (1049.056 us; speedup 1.0000x reference)
//
#include <hip/hip_runtime.h>

// ROUND 11: k2 PROFILING ROUND. k0/k1/k3 byte-identical to round 9, single
// launches. k2 wraps its body in an internal x8 repeat loop (idempotent:
// h_last rewritten identically each rep; rep-boundary barrier via
// unconditional end-of-half __syncthreads). k2's dispatch now runs ~8x its
// true duration -> it beats the ~160us poison fills into the top-5 and we
// finally get its MfmaUtil/VALUBusy/VGPR/LDS-conflict/FETCH counters.
// dur_us - 541 = 7 * k2.

#define NPATH 8192
#define LMAX  32
#define DIN   256
#define EDIM  128
#define HDIM  128
#define NGRP  1024
#define NTOK  (NPATH * LMAX)   // 262144
#define NCHUNK 512             // 16-row sorted chunks
#define XSLAB ((long)NPATH * EDIM)   // shorts per step-plane
#define K1_TILE 64
#define K1_TPB  16             // tiles per block: 4096 / 256
#define K2_REP  8              // profiling repeat factor

typedef __attribute__((ext_vector_type(8))) short short8;
typedef __attribute__((ext_vector_type(4))) short s16x4;
typedef __attribute__((ext_vector_type(4))) float f32x4;

__device__ __forceinline__ unsigned short f2bf(float f) {
    unsigned int x = __float_as_uint(f);
    x += 0x7fffu + ((x >> 16) & 1u);   // RNE
    return (unsigned short)(x >> 16);
}
__device__ __forceinline__ float sigmoid_f(float x) {
    return __fdividef(1.f, 1.f + __expf(-x));
}
__device__ __forceinline__ float tanh_f(float x) {
    // tanh(x) = 2/(1+e^-2x) - 1  (exact limits at +-inf)
    float t = __expf(-2.f * x);
    return __fdividef(2.f, 1.f + t) - 1.f;
}

// ---------------- K0: counting sort by path length (low-contention) ---------
__global__ __launch_bounds__(512) void k0_sort(const int* __restrict__ lens,
                                               int* __restrict__ perm,
                                               int* __restrict__ inv) {
    __shared__ int hw[8][LMAX];      // per-wave histograms
    __shared__ int startg[8][LMAX];  // per-wave scatter bases
    __shared__ int colsum[LMAX];
    __shared__ int binoff[LMAX];
    const int tid = threadIdx.x;
    const int w = tid >> 6, lane = tid & 63;
    if (lane < LMAX) hw[w][lane] = 0;
    __syncthreads();
    for (int i = tid; i < NPATH; i += 512)
        atomicAdd(&hw[w][lens[i] - 1], 1);          // intra-wave contention only
    __syncthreads();
    if (tid < LMAX) {                                // column scan over waves
        int s = 0;
        #pragma unroll
        for (int ww = 0; ww < 8; ++ww) { startg[ww][tid] = s; s += hw[ww][tid]; }
        colsum[tid] = s;
    }
    __syncthreads();
    if (tid == 0) {                                  // bin exclusive scan
        int s = 0;
        for (int b = 0; b < LMAX; ++b) { binoff[b] = s; s += colsum[b]; }
    }
    __syncthreads();
    if (tid < LMAX) {
        #pragma unroll
        for (int ww = 0; ww < 8; ++ww) startg[ww][tid] += binoff[tid];
    }
    __syncthreads();
    for (int i = tid; i < NPATH; i += 512) {
        int b = lens[i] - 1;
        int p = atomicAdd(&startg[w][b], 1);         // private-wave counter
        perm[p] = i;
        inv[i] = p;
    }
}

// ---------------- K1: persistent projection GEMM + LayerNorm + tanh ---------
// 256 blocks x 512 thr; block handles 16 tiles of 64 tokens. Win staged once;
// A double-buffered; LN pair-exchange; coalesced output via LDS.
__global__ __launch_bounds__(512, 2) void k1_proj(
    const float* __restrict__ inp, const float* __restrict__ Win,
    const float* __restrict__ gam, const float* __restrict__ bet,
    const int* __restrict__ inv, unsigned short* __restrict__ xt)
{
    __shared__ unsigned short Bs[EDIM * DIN];          // 65536 B, swizzled
    __shared__ unsigned short As[2][K1_TILE * DIN];    // 2x32768 B, swizzled
    __shared__ float lnx[2][K1_TILE][2];               // 1024 B: [ch][row][s,ss]
    const int tid = threadIdx.x;
    const int w = tid >> 6, lane = tid & 63, q = lane >> 4, c = lane & 15;
    const int rg = w >> 1, ch = w & 1;                 // rowgroup, colhalf
    const int xr = (c & 7) << 3;

    // ---- stage Win once: bf16, row-swizzled [e][k ^ ((e&7)<<3)] ----
    {
        const int row = tid >> 2, c0 = (tid & 3) * 64;
        const float* src = Win + row * DIN + c0;
        const int key = (row & 7) << 3;
        #pragma unroll
        for (int j = 0; j < 8; ++j) {
            float4 u0 = *(const float4*)(src + j * 8);
            float4 u1 = *(const float4*)(src + j * 8 + 4);
            short8 s;
            s[0] = (short)f2bf(u0.x); s[1] = (short)f2bf(u0.y);
            s[2] = (short)f2bf(u0.z); s[3] = (short)f2bf(u0.w);
            s[4] = (short)f2bf(u1.x); s[5] = (short)f2bf(u1.y);
            s[6] = (short)f2bf(u1.z); s[7] = (short)f2bf(u1.w);
            *(short8*)&Bs[row * DIN + ((c0 + j * 8) ^ key)] = s;
        }
    }

    // staging geometry: thread owns token-row tid>>3, 32 k-cols at (tid&7)*32
    const int arow = tid >> 3, ac0 = (tid & 7) * 32;
    const int akey = (arow & 7) << 3;
    const long tile0 = (long)blockIdx.x * K1_TPB;

    // gamma/beta for this wave's 4 col-tiles (cols ch*64 + i*16 + c)
    float gr[4], br[4];
    #pragma unroll
    for (int i = 0; i < 4; ++i) {
        int col = ch * 64 + i * 16 + c;
        gr[i] = gam[col]; br[i] = bet[col];
    }

    // prologue: stage tile 0 into As[0]
    {
        const float* src = inp + (tile0 * K1_TILE + arow) * DIN + ac0;
        #pragma unroll
        for (int j = 0; j < 4; ++j) {
            float4 u0 = *(const float4*)(src + j * 8);
            float4 u1 = *(const float4*)(src + j * 8 + 4);
            short8 s;
            s[0] = (short)f2bf(u0.x); s[1] = (short)f2bf(u0.y);
            s[2] = (short)f2bf(u0.z); s[3] = (short)f2bf(u0.w);
            s[4] = (short)f2bf(u1.x); s[5] = (short)f2bf(u1.y);
            s[6] = (short)f2bf(u1.z); s[7] = (short)f2bf(u1.w);
            *(short8*)&As[0][arow * DIN + ((ac0 + j * 8) ^ akey)] = s;
        }
    }
    __syncthreads();

    for (int it = 0; it < K1_TPB; ++it) {
        const int cur = it & 1, nxt = cur ^ 1;
        unsigned short* Acur = &As[0][0] + cur * (K1_TILE * DIN);
        unsigned short* Anxt = &As[0][0] + nxt * (K1_TILE * DIN);

        // issue next tile's global loads early (drained after MFMAs)
        float4 fr[8];
        if (it + 1 < K1_TPB) {
            const float* src = inp + ((tile0 + it + 1) * K1_TILE + arow) * DIN + ac0;
            #pragma unroll
            for (int j = 0; j < 8; ++j) fr[j] = *(const float4*)(src + j * 4);
        }

        // MFMA: 16 rows (rg) x 64 cols (ch), K=256
        f32x4 acc[4];
        const f32x4 fzero = {0.f, 0.f, 0.f, 0.f};
        #pragma unroll
        for (int i = 0; i < 4; ++i) acc[i] = fzero;
        const unsigned short* arow_p = &Acur[(rg * 16 + c) * DIN];
        #pragma unroll
        for (int ks = 0; ks < 8; ++ks) {
            short8 a = *(const short8*)(arow_p + ((q * 8 + ks * 32) ^ xr));
            #pragma unroll
            for (int i = 0; i < 4; ++i) {
                short8 b = *(const short8*)&Bs[(ch * 64 + i * 16 + c) * DIN
                                               + ((q * 8 + ks * 32) ^ xr)];
                acc[i] = __builtin_amdgcn_mfma_f32_16x16x32_bf16(a, b, acc[i], 0, 0, 0);
            }
        }

        // LN partials (this colhalf): sum over 4 i in-lane + 16 c-lanes
        float sr[4], qr[4];
        #pragma unroll
        for (int r = 0; r < 4; ++r) {
            float s = 0.f, ss = 0.f;
            #pragma unroll
            for (int i = 0; i < 4; ++i) { float v = acc[i][r]; s += v; ss += v * v; }
            #pragma unroll
            for (int m = 1; m < 16; m <<= 1) { s += __shfl_xor(s, m, 64); ss += __shfl_xor(ss, m, 64); }
            sr[r] = s; qr[r] = ss;
            if (c == 0) { lnx[ch][rg * 16 + q * 4 + r][0] = s; lnx[ch][rg * 16 + q * 4 + r][1] = ss; }
        }
        __syncthreads();   // lnx exchange ready

        // finish LN + tanh, write x~ into Acur (row-swizzled cols 0..127)
        #pragma unroll
        for (int r = 0; r < 4; ++r) {
            const int grow = rg * 16 + q * 4 + r;
            float s = sr[r] + lnx[ch ^ 1][grow][0];
            float ss = qr[r] + lnx[ch ^ 1][grow][1];
            float mu = s * (1.f / 128.f);
            float rstd = rsqrtf(ss * (1.f / 128.f) - mu * mu + 1e-5f);
            const int key = (grow & 7) << 3;
            #pragma unroll
            for (int i = 0; i < 4; ++i) {
                float v = (acc[i][r] - mu) * rstd * gr[i] + br[i];
                Acur[grow * DIN + ((ch * 64 + i * 16 + c) ^ key)] = f2bf(tanh_f(v));
            }
        }

        // write next tile's staged data (vmcnt drains here, post-MFMA)
        if (it + 1 < K1_TPB) {
            #pragma unroll
            for (int j = 0; j < 4; ++j) {
                float4 u0 = fr[j * 2], u1 = fr[j * 2 + 1];
                short8 s;
                s[0] = (short)f2bf(u0.x); s[1] = (short)f2bf(u0.y);
                s[2] = (short)f2bf(u0.z); s[3] = (short)f2bf(u0.w);
                s[4] = (short)f2bf(u1.x); s[5] = (short)f2bf(u1.y);
                s[6] = (short)f2bf(u1.z); s[7] = (short)f2bf(u1.w);
                *(short8*)&Anxt[arow * DIN + ((ac0 + j * 8) ^ akey)] = s;
            }
        }
        __syncthreads();   // x~ complete in Acur; As[nxt] staged

        // coalesced epilogue: thread stores 16 shorts of row tid>>3
        {
            const int row = tid >> 3, e0 = (tid & 7) * 16;
            const int key = (row & 7) << 3;
            short8 v0 = *(const short8*)&Acur[row * DIN + (e0 ^ key)];
            short8 v1 = *(const short8*)&Acur[row * DIN + ((e0 + 8) ^ key)];
            const long m = (tile0 + it) * K1_TILE + row;
            const int path = (int)(m >> 5), t = (int)(m & 31);
            const int slot = inv[path];
            unsigned short* dst = &xt[(long)t * XSLAB + (long)slot * EDIM + e0];
            *(short8*)dst = v0;
            *(short8*)(dst + 8) = v1;
        }
    }
}

// ---------------- K2: LSTM, length-sorted paired 16-row chunks ---------------
// PROFILING: entire body repeated K2_REP times (idempotent). Real k2 time =
// dispatch dur / K2_REP (minus small L3-warmth correction on reps 2+).
__global__ __launch_bounds__(512, 2) void k2_lstm(
    const unsigned short* __restrict__ xt,
    const float* __restrict__ Wih, const float* __restrict__ Whh,
    const float* __restrict__ bih, const float* __restrict__ bhh,
    const int* __restrict__ lens, const int* __restrict__ perm,
    float* __restrict__ h_last)
{
    __shared__ unsigned short wih_s[512 * 128];  // 131072 B, swizzled rows
    __shared__ unsigned short hb[2][16 * 128];   // 8192 B, swizzled rows
    __shared__ unsigned short xb[2][16 * 128];   // 8192 B, swizzled rows
    __shared__ int pemb[16];
    __shared__ int lenb[16];
    const int tid = threadIdx.x;
    const int w = tid >> 6, lane = tid & 63, q = lane >> 4, c = lane & 15;
    const int xr = (c & 7) << 3;   // short-index XOR key for A/B rows (row==c)

    // ---- stage Wih -> LDS as bf16, row-swizzled: [j][k ^ ((j&7)<<3)] ----
    #pragma unroll
    for (int i = 0; i < 32; ++i) {           // 512x128 fp32 = 16384 float4
        int chunk = i * 512 + tid;
        int j = chunk >> 5, c4 = chunk & 31;
        float4 v = *(const float4*)&Wih[j * EDIM + c4 * 4];
        s16x4 s = { (short)f2bf(v.x), (short)f2bf(v.y), (short)f2bf(v.z), (short)f2bf(v.w) };
        *(s16x4*)&wih_s[j * 128 + ((c4 * 4) ^ ((j & 7) << 3))] = s;
    }

    // ---- step-invariant Whh fragments + fused bias, fp32->bf16 into VGPRs ----
    short8 whf[4][4];
    float bs[4];
    #pragma unroll
    for (int g = 0; g < 4; ++g) {
        const int j = g * 128 + w * 16 + c;
        bs[g] = bih[j] + bhh[j];
        const float* ph = Whh + (long)j * HDIM + q * 8;
        #pragma unroll
        for (int ks = 0; ks < 4; ++ks) {
            float4 b0 = *(const float4*)(ph + ks * 32);
            float4 b1 = *(const float4*)(ph + ks * 32 + 4);
            short8 u;
            u[0] = (short)f2bf(b0.x); u[1] = (short)f2bf(b0.y);
            u[2] = (short)f2bf(b0.z); u[3] = (short)f2bf(b0.w);
            u[4] = (short)f2bf(b1.x); u[5] = (short)f2bf(b1.y);
            u[6] = (short)f2bf(b1.z); u[7] = (short)f2bf(b1.w);
            whf[g][ks] = u;
        }
    }

    // step-invariant swizzled k-offsets (shorts): shared by hb/xb/wih reads
    int koff[4];
    #pragma unroll
    for (int ks = 0; ks < 4; ++ks) koff[ks] = (q * 8 + ks * 32) ^ xr;
    const unsigned short* wbase[4];
    #pragma unroll
    for (int g = 0; g < 4; ++g) wbase[g] = &wih_s[(g * 128 + w * 16 + c) * 128];

    // staging indices for the 8B/thread x-tile copy (4KB per step)
    const int srow = tid >> 5;                 // 0..15
    const int scol = (tid * 4) & 127;          // 4-short granule
    const int sdst = srow * 128 + (scol ^ ((srow & 7) << 3));

    for (int rep = 0; rep < K2_REP; ++rep) {
    for (int half = 0; half < 2; ++half) {
        // balanced pairing: block b runs sorted chunk b then chunk 511-b
        const int cid = half ? (NCHUNK - 1 - (int)blockIdx.x) : (int)blockIdx.x;
        const int r0 = cid * 16;
        if (tid < 16) { int p = perm[r0 + tid]; pemb[tid] = p; lenb[tid] = lens[p]; }
        { s16x4 z = {0, 0, 0, 0}; *(s16x4*)&hb[0][tid * 4] = z; }  // h(0) = 0
        // pre-stage x(t=0) tile (contiguous 4KB, coalesced)
        {
            s16x4 v = *(const s16x4*)&xt[(long)r0 * EDIM + tid * 4];
            *(s16x4*)&xb[0][sdst] = v;
        }
        __syncthreads();

        int steps = 1;
        #pragma unroll
        for (int i = 0; i < 16; ++i) steps = (lenb[i] > steps) ? lenb[i] : steps;
        int lenr[4];
        #pragma unroll
        for (int r = 0; r < 4; ++r) lenr[r] = lenb[q * 4 + r];

        float c_reg[4] = {0.f, 0.f, 0.f, 0.f};
        float h_reg[4] = {0.f, 0.f, 0.f, 0.f};

        int cur = 0;
        for (int t = 0; t < steps; ++t) {
            // issue next-step x-tile load early (hidden under MFMAs)
            const int tn = (t + 1 < steps) ? (t + 1) : t;
            s16x4 xg = *(const s16x4*)&xt[(long)tn * XSLAB + (long)r0 * EDIM + tid * 4];

            f32x4 acc[4];
            #pragma unroll
            for (int g = 0; g < 4; ++g) {   // bias pre-loaded into accumulator
                f32x4 a = {bs[g], bs[g], bs[g], bs[g]};
                acc[g] = a;
            }
            if (t) {                        // recurrent part (h(0)=0: skip)
                short8 ha[4];
                #pragma unroll
                for (int ks = 0; ks < 4; ++ks)
                    ha[ks] = *(const short8*)&hb[cur][c * 128 + koff[ks]];
                #pragma unroll
                for (int ks = 0; ks < 4; ++ks)
                    #pragma unroll
                    for (int g = 0; g < 4; ++g)
                        acc[g] = __builtin_amdgcn_mfma_f32_16x16x32_bf16(ha[ks], whf[g][ks], acc[g], 0, 0, 0);
            }
            #pragma unroll
            for (int ks = 0; ks < 4; ++ks) {  // input part: A from xb, B from wih_s
                short8 xa = *(const short8*)&xb[cur][c * 128 + koff[ks]];
                #pragma unroll
                for (int g = 0; g < 4; ++g) {
                    short8 b = *(const short8*)(wbase[g] + koff[ks]);
                    acc[g] = __builtin_amdgcn_mfma_f32_16x16x32_bf16(xa, b, acc[g], 0, 0, 0);
                }
            }
            const int nxt = cur ^ 1;
            // write next-step x tile (vmcnt for xg drains here, post-MFMA)
            *(s16x4*)&xb[nxt][sdst] = xg;

            #pragma unroll
            for (int r = 0; r < 4; ++r) {   // acc[g][r]: row q*4+r, gate g
                float cn = sigmoid_f(acc[1][r]) * c_reg[r]
                         + sigmoid_f(acc[0][r]) * tanh_f(acc[2][r]);
                float hn = sigmoid_f(acc[3][r]) * tanh_f(cn);
                if (t < lenr[r]) { c_reg[r] = cn; h_reg[r] = hn; }
                const int row = q * 4 + r;
                hb[nxt][row * 128 + ((w * 16 + c) ^ ((row & 7) << 3))] = f2bf(h_reg[r]);
            }
            __syncthreads();                // single barrier per step (dbuf)
            cur = nxt;
        }
        #pragma unroll
        for (int r = 0; r < 4; ++r)
            h_last[(long)pemb[q * 4 + r] * HDIM + w * 16 + c] = h_reg[r];
        __syncthreads();   // pemb/lenb/hb/xb reused by next half AND next rep
    }
    }
}

// ---------------- K3: segmented softmax attention + output GEMMs (fp32 out) -
__global__ __launch_bounds__(64) void k3_attn(
    const float* __restrict__ h_last, const int* __restrict__ seg,
    const float* __restrict__ attn, const float* __restrict__ Wout,
    const float* __restrict__ Wcls, float* __restrict__ out)
{
    __shared__ float code_s[128];
    const int g = blockIdx.x, l = threadIdx.x;

    int lo, hi;
    { int a = 0, b = NPATH; while (a < b) { int m = (a + b) >> 1; if (seg[m] < g) a = m + 1; else b = m; } lo = a; }
    { int a = lo, b = NPATH; while (a < b) { int m = (a + b) >> 1; if (seg[m] < g + 1) a = m + 1; else b = m; } hi = a; }

    float a0 = attn[l], a1 = attn[l + 64];
    float mrun = -1e30f, Z = 0.f;
    for (int n = lo; n < hi; ++n) {        // online softmax stats
        const float* hr = &h_last[(long)n * HDIM];
        float v = hr[l] * a0 + hr[l + 64] * a1;
        #pragma unroll
        for (int m = 1; m < 64; m <<= 1) v += __shfl_xor(v, m, 64);
        float nm = fmaxf(mrun, v);
        Z = Z * __expf(mrun - nm) + __expf(v - nm);
        mrun = nm;
    }
    float w0 = 0.f, w1 = 0.f;
    for (int n = lo; n < hi; ++n) {        // weighted sum
        const float* hr = &h_last[(long)n * HDIM];
        float v = hr[l] * a0 + hr[l + 64] * a1;
        #pragma unroll
        for (int m = 1; m < 64; m <<= 1) v += __shfl_xor(v, m, 64);
        float at = __expf(v - mrun) / Z;
        w0 += at * hr[l]; w1 += at * hr[l + 64];
    }
    float inv_cnt = (hi > lo) ? 1.f / (float)(hi - lo) : 0.f;
    code_s[l] = w0 * inv_cnt; code_s[l + 64] = w1 * inv_cnt;
    __syncthreads();

    float cv0 = 0.f, cv1 = 0.f;            // code @ W_out.T
    for (int k = 0; k < 128; ++k) {
        float ck = code_s[k];
        cv0 += ck * Wout[l * 128 + k];
        cv1 += ck * Wout[(l + 64) * 128 + k];
    }
    out[2048 + g * 128 + l]      = cv0;
    out[2048 + g * 128 + l + 64] = cv1;

    float p0 = cv0 * Wcls[l] + cv1 * Wcls[l + 64];          // cv @ W_cls.T
    float p1 = cv0 * Wcls[128 + l] + cv1 * Wcls[128 + l + 64];
    #pragma unroll
    for (int m = 1; m < 64; m <<= 1) { p0 += __shfl_xor(p0, m, 64); p1 += __shfl_xor(p1, m, 64); }
    if (l == 0) { out[g * 2 + 0] = p0; out[g * 2 + 1] = p1; }
    if (g == 0) { out[133120 + l] = attn[l]; out[133120 + 64 + l] = attn[l + 64]; }
}

extern "C" void kernel_launch(void* const* d_in, const int* in_sizes, int n_in,
                              void* d_out, int out_size, void* d_ws, size_t ws_size,
                              hipStream_t stream) {
    const float* inp  = (const float*)d_in[0];
    const int*   lens = (const int*)d_in[1];
    const int*   seg  = (const int*)d_in[2];
    const float* Win  = (const float*)d_in[3];
    const float* gam  = (const float*)d_in[4];
    const float* bet  = (const float*)d_in[5];
    const float* Wih  = (const float*)d_in[6];
    const float* Whh  = (const float*)d_in[7];
    const float* bih  = (const float*)d_in[8];
    const float* bhh  = (const float*)d_in[9];
    const float* attn = (const float*)d_in[10];
    const float* Wout = (const float*)d_in[11];
    const float* Wcls = (const float*)d_in[12];

    unsigned short* xt = (unsigned short*)d_ws;                               // 64 MB bf16 x~ [t][slot][E]
    float* h_last = (float*)((char*)d_ws + (size_t)NTOK * EDIM * 2);          // 4 MB f32
    int* perm = (int*)((char*)d_ws + (size_t)NTOK * EDIM * 2
                                   + (size_t)NPATH * HDIM * 4);               // 32 KB
    int* inv  = perm + NPATH;                                                 // 32 KB

    hipLaunchKernelGGL(k0_sort, dim3(1), dim3(512), 0, stream, lens, perm, inv);
    hipLaunchKernelGGL(k1_proj, dim3(256), dim3(512), 0, stream, inp, Win, gam, bet, inv, xt);
    hipLaunchKernelGGL(k2_lstm, dim3(NCHUNK / 2), dim3(512), 0, stream,
                       xt, Wih, Whh, bih, bhh, lens, perm, h_last);
    hipLaunchKernelGGL(k3_attn, dim3(NGRP), dim3(64), 0, stream, h_last, seg, attn, Wout, Wcls,
                       (float*)d_out);
}

// Round 8
// 587.052 us; speedup vs baseline: 1.7870x; 1.7870x over previous
//
#include <hip/hip_runtime.h>

// ROUND 12: k2 structural rewrite from measured counters (r11: MfmaUtil 18%,
// VALUBusy 60%, 5.1e7 bank conflicts, k2 ~110us single-pass).
//  - 32-row chunks, ONE chunk per block (256 blocks): halves barrier count
//    per row of work; wall = 32 steps (longest chunk) as before.
//  - kb-subtile LDS layout (cell = kb*rows + row, 16B cells) for hb/xb/wih:
//    wave reads = 4 contiguous 256B streams -> conflict-free (old XOR swizzle
//    left q unspread -> 8-way aliasing, 12% of cycles).
//  - Wih gates i,f in LDS (64KB kb-subtiled); gates g,o in VGPRs (+32 regs);
//    Whh in VGPRs (unchanged). LDS 98.5KB, VGPR ~200.
//  - Same accumulation order -> bit-identical output.
// k0/k1/k3 byte-identical to round 9.

#define NPATH 8192
#define LMAX  32
#define DIN   256
#define EDIM  128
#define HDIM  128
#define NGRP  1024
#define NTOK  (NPATH * LMAX)   // 262144
#define XSLAB ((long)NPATH * EDIM)   // shorts per step-plane
#define K1_TILE 64
#define K1_TPB  16             // tiles per block: 4096 / 256
#define NCH32 256              // 32-row sorted chunks

typedef __attribute__((ext_vector_type(8))) short short8;
typedef __attribute__((ext_vector_type(4))) short s16x4;
typedef __attribute__((ext_vector_type(4))) float f32x4;

__device__ __forceinline__ unsigned short f2bf(float f) {
    unsigned int x = __float_as_uint(f);
    x += 0x7fffu + ((x >> 16) & 1u);   // RNE
    return (unsigned short)(x >> 16);
}
__device__ __forceinline__ float sigmoid_f(float x) {
    return __fdividef(1.f, 1.f + __expf(-x));
}
__device__ __forceinline__ float tanh_f(float x) {
    // tanh(x) = 2/(1+e^-2x) - 1  (exact limits at +-inf)
    float t = __expf(-2.f * x);
    return __fdividef(2.f, 1.f + t) - 1.f;
}

// ---------------- K0: counting sort by path length (low-contention) ---------
__global__ __launch_bounds__(512) void k0_sort(const int* __restrict__ lens,
                                               int* __restrict__ perm,
                                               int* __restrict__ inv) {
    __shared__ int hw[8][LMAX];      // per-wave histograms
    __shared__ int startg[8][LMAX];  // per-wave scatter bases
    __shared__ int colsum[LMAX];
    __shared__ int binoff[LMAX];
    const int tid = threadIdx.x;
    const int w = tid >> 6, lane = tid & 63;
    if (lane < LMAX) hw[w][lane] = 0;
    __syncthreads();
    for (int i = tid; i < NPATH; i += 512)
        atomicAdd(&hw[w][lens[i] - 1], 1);          // intra-wave contention only
    __syncthreads();
    if (tid < LMAX) {                                // column scan over waves
        int s = 0;
        #pragma unroll
        for (int ww = 0; ww < 8; ++ww) { startg[ww][tid] = s; s += hw[ww][tid]; }
        colsum[tid] = s;
    }
    __syncthreads();
    if (tid == 0) {                                  // bin exclusive scan
        int s = 0;
        for (int b = 0; b < LMAX; ++b) { binoff[b] = s; s += colsum[b]; }
    }
    __syncthreads();
    if (tid < LMAX) {
        #pragma unroll
        for (int ww = 0; ww < 8; ++ww) startg[ww][tid] += binoff[tid];
    }
    __syncthreads();
    for (int i = tid; i < NPATH; i += 512) {
        int b = lens[i] - 1;
        int p = atomicAdd(&startg[w][b], 1);         // private-wave counter
        perm[p] = i;
        inv[i] = p;
    }
}

// ---------------- K1: persistent projection GEMM + LayerNorm + tanh ---------
// 256 blocks x 512 thr; block handles 16 tiles of 64 tokens. Win staged once;
// A double-buffered; LN pair-exchange; coalesced output via LDS.
__global__ __launch_bounds__(512, 2) void k1_proj(
    const float* __restrict__ inp, const float* __restrict__ Win,
    const float* __restrict__ gam, const float* __restrict__ bet,
    const int* __restrict__ inv, unsigned short* __restrict__ xt)
{
    __shared__ unsigned short Bs[EDIM * DIN];          // 65536 B, swizzled
    __shared__ unsigned short As[2][K1_TILE * DIN];    // 2x32768 B, swizzled
    __shared__ float lnx[2][K1_TILE][2];               // 1024 B: [ch][row][s,ss]
    const int tid = threadIdx.x;
    const int w = tid >> 6, lane = tid & 63, q = lane >> 4, c = lane & 15;
    const int rg = w >> 1, ch = w & 1;                 // rowgroup, colhalf
    const int xr = (c & 7) << 3;

    // ---- stage Win once: bf16, row-swizzled [e][k ^ ((e&7)<<3)] ----
    {
        const int row = tid >> 2, c0 = (tid & 3) * 64;
        const float* src = Win + row * DIN + c0;
        const int key = (row & 7) << 3;
        #pragma unroll
        for (int j = 0; j < 8; ++j) {
            float4 u0 = *(const float4*)(src + j * 8);
            float4 u1 = *(const float4*)(src + j * 8 + 4);
            short8 s;
            s[0] = (short)f2bf(u0.x); s[1] = (short)f2bf(u0.y);
            s[2] = (short)f2bf(u0.z); s[3] = (short)f2bf(u0.w);
            s[4] = (short)f2bf(u1.x); s[5] = (short)f2bf(u1.y);
            s[6] = (short)f2bf(u1.z); s[7] = (short)f2bf(u1.w);
            *(short8*)&Bs[row * DIN + ((c0 + j * 8) ^ key)] = s;
        }
    }

    // staging geometry: thread owns token-row tid>>3, 32 k-cols at (tid&7)*32
    const int arow = tid >> 3, ac0 = (tid & 7) * 32;
    const int akey = (arow & 7) << 3;
    const long tile0 = (long)blockIdx.x * K1_TPB;

    // gamma/beta for this wave's 4 col-tiles (cols ch*64 + i*16 + c)
    float gr[4], br[4];
    #pragma unroll
    for (int i = 0; i < 4; ++i) {
        int col = ch * 64 + i * 16 + c;
        gr[i] = gam[col]; br[i] = bet[col];
    }

    // prologue: stage tile 0 into As[0]
    {
        const float* src = inp + (tile0 * K1_TILE + arow) * DIN + ac0;
        #pragma unroll
        for (int j = 0; j < 4; ++j) {
            float4 u0 = *(const float4*)(src + j * 8);
            float4 u1 = *(const float4*)(src + j * 8 + 4);
            short8 s;
            s[0] = (short)f2bf(u0.x); s[1] = (short)f2bf(u0.y);
            s[2] = (short)f2bf(u0.z); s[3] = (short)f2bf(u0.w);
            s[4] = (short)f2bf(u1.x); s[5] = (short)f2bf(u1.y);
            s[6] = (short)f2bf(u1.z); s[7] = (short)f2bf(u1.w);
            *(short8*)&As[0][arow * DIN + ((ac0 + j * 8) ^ akey)] = s;
        }
    }
    __syncthreads();

    for (int it = 0; it < K1_TPB; ++it) {
        const int cur = it & 1, nxt = cur ^ 1;
        unsigned short* Acur = &As[0][0] + cur * (K1_TILE * DIN);
        unsigned short* Anxt = &As[0][0] + nxt * (K1_TILE * DIN);

        // issue next tile's global loads early (drained after MFMAs)
        float4 fr[8];
        if (it + 1 < K1_TPB) {
            const float* src = inp + ((tile0 + it + 1) * K1_TILE + arow) * DIN + ac0;
            #pragma unroll
            for (int j = 0; j < 8; ++j) fr[j] = *(const float4*)(src + j * 4);
        }

        // MFMA: 16 rows (rg) x 64 cols (ch), K=256
        f32x4 acc[4];
        const f32x4 fzero = {0.f, 0.f, 0.f, 0.f};
        #pragma unroll
        for (int i = 0; i < 4; ++i) acc[i] = fzero;
        const unsigned short* arow_p = &Acur[(rg * 16 + c) * DIN];
        #pragma unroll
        for (int ks = 0; ks < 8; ++ks) {
            short8 a = *(const short8*)(arow_p + ((q * 8 + ks * 32) ^ xr));
            #pragma unroll
            for (int i = 0; i < 4; ++i) {
                short8 b = *(const short8*)&Bs[(ch * 64 + i * 16 + c) * DIN
                                               + ((q * 8 + ks * 32) ^ xr)];
                acc[i] = __builtin_amdgcn_mfma_f32_16x16x32_bf16(a, b, acc[i], 0, 0, 0);
            }
        }

        // LN partials (this colhalf): sum over 4 i in-lane + 16 c-lanes
        float sr[4], qr[4];
        #pragma unroll
        for (int r = 0; r < 4; ++r) {
            float s = 0.f, ss = 0.f;
            #pragma unroll
            for (int i = 0; i < 4; ++i) { float v = acc[i][r]; s += v; ss += v * v; }
            #pragma unroll
            for (int m = 1; m < 16; m <<= 1) { s += __shfl_xor(s, m, 64); ss += __shfl_xor(ss, m, 64); }
            sr[r] = s; qr[r] = ss;
            if (c == 0) { lnx[ch][rg * 16 + q * 4 + r][0] = s; lnx[ch][rg * 16 + q * 4 + r][1] = ss; }
        }
        __syncthreads();   // lnx exchange ready

        // finish LN + tanh, write x~ into Acur (row-swizzled cols 0..127)
        #pragma unroll
        for (int r = 0; r < 4; ++r) {
            const int grow = rg * 16 + q * 4 + r;
            float s = sr[r] + lnx[ch ^ 1][grow][0];
            float ss = qr[r] + lnx[ch ^ 1][grow][1];
            float mu = s * (1.f / 128.f);
            float rstd = rsqrtf(ss * (1.f / 128.f) - mu * mu + 1e-5f);
            const int key = (grow & 7) << 3;
            #pragma unroll
            for (int i = 0; i < 4; ++i) {
                float v = (acc[i][r] - mu) * rstd * gr[i] + br[i];
                Acur[grow * DIN + ((ch * 64 + i * 16 + c) ^ key)] = f2bf(tanh_f(v));
            }
        }

        // write next tile's staged data (vmcnt drains here, post-MFMA)
        if (it + 1 < K1_TPB) {
            #pragma unroll
            for (int j = 0; j < 4; ++j) {
                float4 u0 = fr[j * 2], u1 = fr[j * 2 + 1];
                short8 s;
                s[0] = (short)f2bf(u0.x); s[1] = (short)f2bf(u0.y);
                s[2] = (short)f2bf(u0.z); s[3] = (short)f2bf(u0.w);
                s[4] = (short)f2bf(u1.x); s[5] = (short)f2bf(u1.y);
                s[6] = (short)f2bf(u1.z); s[7] = (short)f2bf(u1.w);
                *(short8*)&Anxt[arow * DIN + ((ac0 + j * 8) ^ akey)] = s;
            }
        }
        __syncthreads();   // x~ complete in Acur; As[nxt] staged

        // coalesced epilogue: thread stores 16 shorts of row tid>>3
        {
            const int row = tid >> 3, e0 = (tid & 7) * 16;
            const int key = (row & 7) << 3;
            short8 v0 = *(const short8*)&Acur[row * DIN + (e0 ^ key)];
            short8 v1 = *(const short8*)&Acur[row * DIN + ((e0 + 8) ^ key)];
            const long m = (tile0 + it) * K1_TILE + row;
            const int path = (int)(m >> 5), t = (int)(m & 31);
            const int slot = inv[path];
            unsigned short* dst = &xt[(long)t * XSLAB + (long)slot * EDIM + e0];
            *(short8*)dst = v0;
            *(short8*)(dst + 8) = v1;
        }
    }
}

// ---------------- K2: LSTM, 32-row sorted chunk per block ------------------
// 8 waves: wave w owns gate-cols g*128 + w*16 + c. A rows: m*16 + c (m=0,1).
// Whh + Wih(gates g,o) fragments in VGPRs; Wih(gates i,f) in kb-subtile LDS;
// h and x tiles in kb-subtile double-buffered LDS; one barrier per step.
__global__ __launch_bounds__(512, 2) void k2_lstm(
    const unsigned short* __restrict__ xt,
    const float* __restrict__ Wih, const float* __restrict__ Whh,
    const float* __restrict__ bih, const float* __restrict__ bhh,
    const int* __restrict__ lens, const int* __restrict__ perm,
    float* __restrict__ h_last)
{
    __shared__ unsigned short wih2[16 * 256 * 8];   // 65536 B: [kb][j2][8], gates i,f
    __shared__ unsigned short hb2[2][16 * 32 * 8];  // 2x8192 B: [kb][row][8]
    __shared__ unsigned short xb2[2][16 * 32 * 8];  // 2x8192 B: [kb][row][8]
    __shared__ int pemb[32];
    __shared__ int lenb[32];
    const int tid = threadIdx.x;
    const int w = tid >> 6, lane = tid & 63, q = lane >> 4, c = lane & 15;

    // ---- stage Wih gates 0,1 (rows 0..255) -> kb-subtile LDS ----
    #pragma unroll
    for (int i = 0; i < 16; ++i) {           // 256x128 fp32 = 8192 float4
        int chunk = i * 512 + tid;
        int j2 = chunk >> 5, c4 = chunk & 31;
        float4 v = *(const float4*)&Wih[j2 * EDIM + c4 * 4];
        s16x4 s = { (short)f2bf(v.x), (short)f2bf(v.y), (short)f2bf(v.z), (short)f2bf(v.w) };
        *(s16x4*)&wih2[((c4 >> 1) * 256 + j2) * 8 + (c4 & 1) * 4] = s;
    }

    // ---- step-invariant VGPR fragments: Whh (all gates) + Wih gates 2,3 ----
    short8 whf[4][4];   // Whh
    short8 wfv[2][4];   // Wih gates g,o
    float bs[4];
    #pragma unroll
    for (int g = 0; g < 4; ++g) {
        const int j = g * 128 + w * 16 + c;
        bs[g] = bih[j] + bhh[j];
        const float* ph = Whh + (long)j * HDIM + q * 8;
        #pragma unroll
        for (int ks = 0; ks < 4; ++ks) {
            float4 b0 = *(const float4*)(ph + ks * 32);
            float4 b1 = *(const float4*)(ph + ks * 32 + 4);
            short8 u;
            u[0] = (short)f2bf(b0.x); u[1] = (short)f2bf(b0.y);
            u[2] = (short)f2bf(b0.z); u[3] = (short)f2bf(b0.w);
            u[4] = (short)f2bf(b1.x); u[5] = (short)f2bf(b1.y);
            u[6] = (short)f2bf(b1.z); u[7] = (short)f2bf(b1.w);
            whf[g][ks] = u;
        }
    }
    #pragma unroll
    for (int gi = 0; gi < 2; ++gi) {
        const int j = (2 + gi) * 128 + w * 16 + c;
        const float* pi = Wih + (long)j * EDIM + q * 8;
        #pragma unroll
        for (int ks = 0; ks < 4; ++ks) {
            float4 a0 = *(const float4*)(pi + ks * 32);
            float4 a1 = *(const float4*)(pi + ks * 32 + 4);
            short8 s;
            s[0] = (short)f2bf(a0.x); s[1] = (short)f2bf(a0.y);
            s[2] = (short)f2bf(a0.z); s[3] = (short)f2bf(a0.w);
            s[4] = (short)f2bf(a1.x); s[5] = (short)f2bf(a1.y);
            s[6] = (short)f2bf(a1.z); s[7] = (short)f2bf(a1.w);
            wfv[gi][ks] = s;
        }
    }

    const int r0 = blockIdx.x * 32;
    if (tid < 32) { int p = perm[r0 + tid]; pemb[tid] = p; lenb[tid] = lens[p]; }
    // staging geometry: thread stages 16B: row = tid>>4, kb = tid&15
    const int srow = tid >> 4, skb = tid & 15;
    const int sdst = (skb * 32 + srow) * 8;
    {   // pre-stage x(t=0): coalesced (4 x 256B segments per wave)
        short8 v = *(const short8*)&xt[(long)(r0 + srow) * EDIM + skb * 8];
        *(short8*)&xb2[0][sdst] = v;
    }
    __syncthreads();

    const int steps = lenb[31];              // chunk rows sorted ascending
    int lenr[2][4];
    #pragma unroll
    for (int m = 0; m < 2; ++m)
        #pragma unroll
        for (int r = 0; r < 4; ++r) lenr[m][r] = lenb[m * 16 + q * 4 + r];

    float c_reg[2][4] = {{0.f,0.f,0.f,0.f},{0.f,0.f,0.f,0.f}};
    float h_reg[2][4] = {{0.f,0.f,0.f,0.f},{0.f,0.f,0.f,0.f}};

    int cur = 0;
    for (int t = 0; t < steps; ++t) {
        // issue next-step x-tile load early (hidden under MFMAs)
        const int tn = (t + 1 < steps) ? (t + 1) : t;
        short8 xg = *(const short8*)&xt[(long)tn * XSLAB + (long)(r0 + srow) * EDIM + skb * 8];

        f32x4 acc[2][4];
        #pragma unroll
        for (int m = 0; m < 2; ++m)
            #pragma unroll
            for (int g = 0; g < 4; ++g) {   // bias pre-loaded into accumulator
                f32x4 a = {bs[g], bs[g], bs[g], bs[g]};
                acc[m][g] = a;
            }
        if (t) {                            // recurrent part (h(0)=0: skip)
            #pragma unroll
            for (int ks = 0; ks < 4; ++ks) {
                short8 ha0 = *(const short8*)&hb2[cur][((q + 4 * ks) * 32 + c) * 8];
                short8 ha1 = *(const short8*)&hb2[cur][((q + 4 * ks) * 32 + 16 + c) * 8];
                #pragma unroll
                for (int g = 0; g < 4; ++g) {
                    acc[0][g] = __builtin_amdgcn_mfma_f32_16x16x32_bf16(ha0, whf[g][ks], acc[0][g], 0, 0, 0);
                    acc[1][g] = __builtin_amdgcn_mfma_f32_16x16x32_bf16(ha1, whf[g][ks], acc[1][g], 0, 0, 0);
                }
            }
        }
        #pragma unroll
        for (int ks = 0; ks < 4; ++ks) {    // input part
            short8 xa0 = *(const short8*)&xb2[cur][((q + 4 * ks) * 32 + c) * 8];
            short8 xa1 = *(const short8*)&xb2[cur][((q + 4 * ks) * 32 + 16 + c) * 8];
            short8 b0 = *(const short8*)&wih2[((q + 4 * ks) * 256 + w * 16 + c) * 8];
            short8 b1 = *(const short8*)&wih2[((q + 4 * ks) * 256 + 128 + w * 16 + c) * 8];
            acc[0][0] = __builtin_amdgcn_mfma_f32_16x16x32_bf16(xa0, b0, acc[0][0], 0, 0, 0);
            acc[1][0] = __builtin_amdgcn_mfma_f32_16x16x32_bf16(xa1, b0, acc[1][0], 0, 0, 0);
            acc[0][1] = __builtin_amdgcn_mfma_f32_16x16x32_bf16(xa0, b1, acc[0][1], 0, 0, 0);
            acc[1][1] = __builtin_amdgcn_mfma_f32_16x16x32_bf16(xa1, b1, acc[1][1], 0, 0, 0);
            acc[0][2] = __builtin_amdgcn_mfma_f32_16x16x32_bf16(xa0, wfv[0][ks], acc[0][2], 0, 0, 0);
            acc[1][2] = __builtin_amdgcn_mfma_f32_16x16x32_bf16(xa1, wfv[0][ks], acc[1][2], 0, 0, 0);
            acc[0][3] = __builtin_amdgcn_mfma_f32_16x16x32_bf16(xa0, wfv[1][ks], acc[0][3], 0, 0, 0);
            acc[1][3] = __builtin_amdgcn_mfma_f32_16x16x32_bf16(xa1, wfv[1][ks], acc[1][3], 0, 0, 0);
        }
        const int nxt = cur ^ 1;
        // write next-step x tile (vmcnt for xg drains here, post-MFMA)
        *(short8*)&xb2[nxt][sdst] = xg;

        #pragma unroll
        for (int m = 0; m < 2; ++m)
            #pragma unroll
            for (int r = 0; r < 4; ++r) {   // acc[m][g][r]: row m*16+q*4+r
                float cn = sigmoid_f(acc[m][1][r]) * c_reg[m][r]
                         + sigmoid_f(acc[m][0][r]) * tanh_f(acc[m][2][r]);
                float hn = sigmoid_f(acc[m][3][r]) * tanh_f(cn);
                if (t < lenr[m][r]) { c_reg[m][r] = cn; h_reg[m][r] = hn; }
                const int row = m * 16 + q * 4 + r;
                const int kb = w * 2 + (c >> 3);
                hb2[nxt][(kb * 32 + row) * 8 + (c & 7)] = f2bf(h_reg[m][r]);
            }
        __syncthreads();                    // single barrier per step (dbuf)
        cur = nxt;
    }

    #pragma unroll
    for (int m = 0; m < 2; ++m)
        #pragma unroll
        for (int r = 0; r < 4; ++r)
            h_last[(long)pemb[m * 16 + q * 4 + r] * HDIM + w * 16 + c] = h_reg[m][r];
}

// ---------------- K3: segmented softmax attention + output GEMMs (fp32 out) -
__global__ __launch_bounds__(64) void k3_attn(
    const float* __restrict__ h_last, const int* __restrict__ seg,
    const float* __restrict__ attn, const float* __restrict__ Wout,
    const float* __restrict__ Wcls, float* __restrict__ out)
{
    __shared__ float code_s[128];
    const int g = blockIdx.x, l = threadIdx.x;

    int lo, hi;
    { int a = 0, b = NPATH; while (a < b) { int m = (a + b) >> 1; if (seg[m] < g) a = m + 1; else b = m; } lo = a; }
    { int a = lo, b = NPATH; while (a < b) { int m = (a + b) >> 1; if (seg[m] < g + 1) a = m + 1; else b = m; } hi = a; }

    float a0 = attn[l], a1 = attn[l + 64];
    float mrun = -1e30f, Z = 0.f;
    for (int n = lo; n < hi; ++n) {        // online softmax stats
        const float* hr = &h_last[(long)n * HDIM];
        float v = hr[l] * a0 + hr[l + 64] * a1;
        #pragma unroll
        for (int m = 1; m < 64; m <<= 1) v += __shfl_xor(v, m, 64);
        float nm = fmaxf(mrun, v);
        Z = Z * __expf(mrun - nm) + __expf(v - nm);
        mrun = nm;
    }
    float w0 = 0.f, w1 = 0.f;
    for (int n = lo; n < hi; ++n) {        // weighted sum
        const float* hr = &h_last[(long)n * HDIM];
        float v = hr[l] * a0 + hr[l + 64] * a1;
        #pragma unroll
        for (int m = 1; m < 64; m <<= 1) v += __shfl_xor(v, m, 64);
        float at = __expf(v - mrun) / Z;
        w0 += at * hr[l]; w1 += at * hr[l + 64];
    }
    float inv_cnt = (hi > lo) ? 1.f / (float)(hi - lo) : 0.f;
    code_s[l] = w0 * inv_cnt; code_s[l + 64] = w1 * inv_cnt;
    __syncthreads();

    float cv0 = 0.f, cv1 = 0.f;            // code @ W_out.T
    for (int k = 0; k < 128; ++k) {
        float ck = code_s[k];
        cv0 += ck * Wout[l * 128 + k];
        cv1 += ck * Wout[(l + 64) * 128 + k];
    }
    out[2048 + g * 128 + l]      = cv0;
    out[2048 + g * 128 + l + 64] = cv1;

    float p0 = cv0 * Wcls[l] + cv1 * Wcls[l + 64];          // cv @ W_cls.T
    float p1 = cv0 * Wcls[128 + l] + cv1 * Wcls[128 + l + 64];
    #pragma unroll
    for (int m = 1; m < 64; m <<= 1) { p0 += __shfl_xor(p0, m, 64); p1 += __shfl_xor(p1, m, 64); }
    if (l == 0) { out[g * 2 + 0] = p0; out[g * 2 + 1] = p1; }
    if (g == 0) { out[133120 + l] = attn[l]; out[133120 + 64 + l] = attn[l + 64]; }
}

extern "C" void kernel_launch(void* const* d_in, const int* in_sizes, int n_in,
                              void* d_out, int out_size, void* d_ws, size_t ws_size,
                              hipStream_t stream) {
    const float* inp  = (const float*)d_in[0];
    const int*   lens = (const int*)d_in[1];
    const int*   seg  = (const int*)d_in[2];
    const float* Win  = (const float*)d_in[3];
    const float* gam  = (const float*)d_in[4];
    const float* bet  = (const float*)d_in[5];
    const float* Wih  = (const float*)d_in[6];
    const float* Whh  = (const float*)d_in[7];
    const float* bih  = (const float*)d_in[8];
    const float* bhh  = (const float*)d_in[9];
    const float* attn = (const float*)d_in[10];
    const float* Wout = (const float*)d_in[11];
    const float* Wcls = (const float*)d_in[12];

    unsigned short* xt = (unsigned short*)d_ws;                               // 64 MB bf16 x~ [t][slot][E]
    float* h_last = (float*)((char*)d_ws + (size_t)NTOK * EDIM * 2);          // 4 MB f32
    int* perm = (int*)((char*)d_ws + (size_t)NTOK * EDIM * 2
                                   + (size_t)NPATH * HDIM * 4);               // 32 KB
    int* inv  = perm + NPATH;                                                 // 32 KB

    hipLaunchKernelGGL(k0_sort, dim3(1), dim3(512), 0, stream, lens, perm, inv);
    hipLaunchKernelGGL(k1_proj, dim3(256), dim3(512), 0, stream, inp, Win, gam, bet, inv, xt);
    hipLaunchKernelGGL(k2_lstm, dim3(NCH32), dim3(512), 0, stream,
                       xt, Wih, Whh, bih, bhh, lens, perm, h_last);
    hipLaunchKernelGGL(k3_attn, dim3(NGRP), dim3(64), 0, stream, h_last, seg, attn, Wout, Wcls,
                       (float*)d_out);
}

// Round 9
// 498.208 us; speedup vs baseline: 2.1057x; 1.1783x over previous
//
#include <hip/hip_runtime.h>

// ROUND 13: revert k2 to balanced paired 16-row chunks (r12's 32-row chunk
// doubled the wall's work: 169us; per-16-row-step cost 6300cyc was INVARIANT
// across all layout changes -> VALU-bound per r11 counters, VALUBusy 60%).
//  - k2 structure: 256 blocks x (chunk b, chunk 511-b), 16 rows/step, 33 wall
//    steps; kb-subtile LDS (r12's verified layout, conflict-free); Wih gates
//    i,f in LDS (64KB), gates g,o + Whh in VGPRs; LDS 80KB.
//  - VALU diet on the critical path: raw v_exp_f32/v_rcp_f32 (1-instr inline
//    asm) replace __expf/__fdividef expansions in sigmoid/tanh; x-plane
//    pointer increments replace per-step 64-bit mads.
// k0/k1/k3 byte-identical to round 9 (k1/k3 share the cheap act helpers).

#define NPATH 8192
#define LMAX  32
#define DIN   256
#define EDIM  128
#define HDIM  128
#define NGRP  1024
#define NTOK  (NPATH * LMAX)   // 262144
#define XSLAB ((long)NPATH * EDIM)   // shorts per step-plane
#define K1_TILE 64
#define K1_TPB  16             // tiles per block: 4096 / 256
#define NCHUNK 512             // 16-row sorted chunks

typedef __attribute__((ext_vector_type(8))) short short8;
typedef __attribute__((ext_vector_type(4))) short s16x4;
typedef __attribute__((ext_vector_type(4))) float f32x4;

__device__ __forceinline__ unsigned short f2bf(float f) {
    unsigned int x = __float_as_uint(f);
    x += 0x7fffu + ((x >> 16) & 1u);   // RNE
    return (unsigned short)(x >> 16);
}
// raw transcendentals: v_exp_f32 computes 2^x; v_rcp_f32 1/x (ISA §3)
__device__ __forceinline__ float exp2_f(float x) {
    float r; asm("v_exp_f32 %0, %1" : "=v"(r) : "v"(x)); return r;
}
__device__ __forceinline__ float rcp_f(float x) {
    float r; asm("v_rcp_f32 %0, %1" : "=v"(r) : "v"(x)); return r;
}
#define L2E 1.4426950408889634f
__device__ __forceinline__ float sigmoid_f(float x) {
    return rcp_f(1.f + exp2_f(-L2E * x));          // 1/(1+e^-x)
}
__device__ __forceinline__ float tanh_f(float x) {
    return 2.f * rcp_f(1.f + exp2_f(-2.f * L2E * x)) - 1.f;   // 2/(1+e^-2x)-1
}

// ---------------- K0: counting sort by path length (low-contention) ---------
__global__ __launch_bounds__(512) void k0_sort(const int* __restrict__ lens,
                                               int* __restrict__ perm,
                                               int* __restrict__ inv) {
    __shared__ int hw[8][LMAX];      // per-wave histograms
    __shared__ int startg[8][LMAX];  // per-wave scatter bases
    __shared__ int colsum[LMAX];
    __shared__ int binoff[LMAX];
    const int tid = threadIdx.x;
    const int w = tid >> 6, lane = tid & 63;
    if (lane < LMAX) hw[w][lane] = 0;
    __syncthreads();
    for (int i = tid; i < NPATH; i += 512)
        atomicAdd(&hw[w][lens[i] - 1], 1);          // intra-wave contention only
    __syncthreads();
    if (tid < LMAX) {                                // column scan over waves
        int s = 0;
        #pragma unroll
        for (int ww = 0; ww < 8; ++ww) { startg[ww][tid] = s; s += hw[ww][tid]; }
        colsum[tid] = s;
    }
    __syncthreads();
    if (tid == 0) {                                  // bin exclusive scan
        int s = 0;
        for (int b = 0; b < LMAX; ++b) { binoff[b] = s; s += colsum[b]; }
    }
    __syncthreads();
    if (tid < LMAX) {
        #pragma unroll
        for (int ww = 0; ww < 8; ++ww) startg[ww][tid] += binoff[tid];
    }
    __syncthreads();
    for (int i = tid; i < NPATH; i += 512) {
        int b = lens[i] - 1;
        int p = atomicAdd(&startg[w][b], 1);         // private-wave counter
        perm[p] = i;
        inv[i] = p;
    }
}

// ---------------- K1: persistent projection GEMM + LayerNorm + tanh ---------
__global__ __launch_bounds__(512, 2) void k1_proj(
    const float* __restrict__ inp, const float* __restrict__ Win,
    const float* __restrict__ gam, const float* __restrict__ bet,
    const int* __restrict__ inv, unsigned short* __restrict__ xt)
{
    __shared__ unsigned short Bs[EDIM * DIN];          // 65536 B, swizzled
    __shared__ unsigned short As[2][K1_TILE * DIN];    // 2x32768 B, swizzled
    __shared__ float lnx[2][K1_TILE][2];               // 1024 B: [ch][row][s,ss]
    const int tid = threadIdx.x;
    const int w = tid >> 6, lane = tid & 63, q = lane >> 4, c = lane & 15;
    const int rg = w >> 1, ch = w & 1;                 // rowgroup, colhalf
    const int xr = (c & 7) << 3;

    {
        const int row = tid >> 2, c0 = (tid & 3) * 64;
        const float* src = Win + row * DIN + c0;
        const int key = (row & 7) << 3;
        #pragma unroll
        for (int j = 0; j < 8; ++j) {
            float4 u0 = *(const float4*)(src + j * 8);
            float4 u1 = *(const float4*)(src + j * 8 + 4);
            short8 s;
            s[0] = (short)f2bf(u0.x); s[1] = (short)f2bf(u0.y);
            s[2] = (short)f2bf(u0.z); s[3] = (short)f2bf(u0.w);
            s[4] = (short)f2bf(u1.x); s[5] = (short)f2bf(u1.y);
            s[6] = (short)f2bf(u1.z); s[7] = (short)f2bf(u1.w);
            *(short8*)&Bs[row * DIN + ((c0 + j * 8) ^ key)] = s;
        }
    }

    const int arow = tid >> 3, ac0 = (tid & 7) * 32;
    const int akey = (arow & 7) << 3;
    const long tile0 = (long)blockIdx.x * K1_TPB;

    float gr[4], br[4];
    #pragma unroll
    for (int i = 0; i < 4; ++i) {
        int col = ch * 64 + i * 16 + c;
        gr[i] = gam[col]; br[i] = bet[col];
    }

    {
        const float* src = inp + (tile0 * K1_TILE + arow) * DIN + ac0;
        #pragma unroll
        for (int j = 0; j < 4; ++j) {
            float4 u0 = *(const float4*)(src + j * 8);
            float4 u1 = *(const float4*)(src + j * 8 + 4);
            short8 s;
            s[0] = (short)f2bf(u0.x); s[1] = (short)f2bf(u0.y);
            s[2] = (short)f2bf(u0.z); s[3] = (short)f2bf(u0.w);
            s[4] = (short)f2bf(u1.x); s[5] = (short)f2bf(u1.y);
            s[6] = (short)f2bf(u1.z); s[7] = (short)f2bf(u1.w);
            *(short8*)&As[0][arow * DIN + ((ac0 + j * 8) ^ akey)] = s;
        }
    }
    __syncthreads();

    for (int it = 0; it < K1_TPB; ++it) {
        const int cur = it & 1, nxt = cur ^ 1;
        unsigned short* Acur = &As[0][0] + cur * (K1_TILE * DIN);
        unsigned short* Anxt = &As[0][0] + nxt * (K1_TILE * DIN);

        float4 fr[8];
        if (it + 1 < K1_TPB) {
            const float* src = inp + ((tile0 + it + 1) * K1_TILE + arow) * DIN + ac0;
            #pragma unroll
            for (int j = 0; j < 8; ++j) fr[j] = *(const float4*)(src + j * 4);
        }

        f32x4 acc[4];
        const f32x4 fzero = {0.f, 0.f, 0.f, 0.f};
        #pragma unroll
        for (int i = 0; i < 4; ++i) acc[i] = fzero;
        const unsigned short* arow_p = &Acur[(rg * 16 + c) * DIN];
        #pragma unroll
        for (int ks = 0; ks < 8; ++ks) {
            short8 a = *(const short8*)(arow_p + ((q * 8 + ks * 32) ^ xr));
            #pragma unroll
            for (int i = 0; i < 4; ++i) {
                short8 b = *(const short8*)&Bs[(ch * 64 + i * 16 + c) * DIN
                                               + ((q * 8 + ks * 32) ^ xr)];
                acc[i] = __builtin_amdgcn_mfma_f32_16x16x32_bf16(a, b, acc[i], 0, 0, 0);
            }
        }

        float sr[4], qr[4];
        #pragma unroll
        for (int r = 0; r < 4; ++r) {
            float s = 0.f, ss = 0.f;
            #pragma unroll
            for (int i = 0; i < 4; ++i) { float v = acc[i][r]; s += v; ss += v * v; }
            #pragma unroll
            for (int m = 1; m < 16; m <<= 1) { s += __shfl_xor(s, m, 64); ss += __shfl_xor(ss, m, 64); }
            sr[r] = s; qr[r] = ss;
            if (c == 0) { lnx[ch][rg * 16 + q * 4 + r][0] = s; lnx[ch][rg * 16 + q * 4 + r][1] = ss; }
        }
        __syncthreads();

        #pragma unroll
        for (int r = 0; r < 4; ++r) {
            const int grow = rg * 16 + q * 4 + r;
            float s = sr[r] + lnx[ch ^ 1][grow][0];
            float ss = qr[r] + lnx[ch ^ 1][grow][1];
            float mu = s * (1.f / 128.f);
            float rstd = rsqrtf(ss * (1.f / 128.f) - mu * mu + 1e-5f);
            const int key = (grow & 7) << 3;
            #pragma unroll
            for (int i = 0; i < 4; ++i) {
                float v = (acc[i][r] - mu) * rstd * gr[i] + br[i];
                Acur[grow * DIN + ((ch * 64 + i * 16 + c) ^ key)] = f2bf(tanh_f(v));
            }
        }

        if (it + 1 < K1_TPB) {
            #pragma unroll
            for (int j = 0; j < 4; ++j) {
                float4 u0 = fr[j * 2], u1 = fr[j * 2 + 1];
                short8 s;
                s[0] = (short)f2bf(u0.x); s[1] = (short)f2bf(u0.y);
                s[2] = (short)f2bf(u0.z); s[3] = (short)f2bf(u0.w);
                s[4] = (short)f2bf(u1.x); s[5] = (short)f2bf(u1.y);
                s[6] = (short)f2bf(u1.z); s[7] = (short)f2bf(u1.w);
                *(short8*)&Anxt[arow * DIN + ((ac0 + j * 8) ^ akey)] = s;
            }
        }
        __syncthreads();

        {
            const int row = tid >> 3, e0 = (tid & 7) * 16;
            const int key = (row & 7) << 3;
            short8 v0 = *(const short8*)&Acur[row * DIN + (e0 ^ key)];
            short8 v1 = *(const short8*)&Acur[row * DIN + ((e0 + 8) ^ key)];
            const long m = (tile0 + it) * K1_TILE + row;
            const int path = (int)(m >> 5), t = (int)(m & 31);
            const int slot = inv[path];
            unsigned short* dst = &xt[(long)t * XSLAB + (long)slot * EDIM + e0];
            *(short8*)dst = v0;
            *(short8*)(dst + 8) = v1;
        }
    }
}

// ---------------- K2: LSTM, paired 16-row chunks, kb-subtile LDS ------------
// 8 waves: wave w owns gate-cols g*128 + w*16 + c. A rows = c (16 paths).
// Whh + Wih(g,o) in VGPRs; Wih(i,f) in kb-subtile LDS; hb/xb kb-subtile dbuf.
__global__ __launch_bounds__(512, 2) void k2_lstm(
    const unsigned short* __restrict__ xt,
    const float* __restrict__ Wih, const float* __restrict__ Whh,
    const float* __restrict__ bih, const float* __restrict__ bhh,
    const int* __restrict__ lens, const int* __restrict__ perm,
    float* __restrict__ h_last)
{
    __shared__ unsigned short wih2[16 * 256 * 8];   // 65536 B: [kb][j2][8], gates i,f
    __shared__ unsigned short hb2[2][16 * 16 * 8];  // 2x4096 B: [kb][row][8]
    __shared__ unsigned short xb2[2][16 * 16 * 8];  // 2x4096 B: [kb][row][8]
    __shared__ int pemb[16];
    __shared__ int lenb[16];
    const int tid = threadIdx.x;
    const int w = tid >> 6, lane = tid & 63, q = lane >> 4, c = lane & 15;

    // ---- stage Wih gates 0,1 (rows 0..255) -> kb-subtile LDS ----
    #pragma unroll
    for (int i = 0; i < 16; ++i) {           // 256x128 fp32 = 8192 float4
        int chunk = i * 512 + tid;
        int j2 = chunk >> 5, c4 = chunk & 31;
        float4 v = *(const float4*)&Wih[j2 * EDIM + c4 * 4];
        s16x4 s = { (short)f2bf(v.x), (short)f2bf(v.y), (short)f2bf(v.z), (short)f2bf(v.w) };
        *(s16x4*)&wih2[((c4 >> 1) * 256 + j2) * 8 + (c4 & 1) * 4] = s;
    }

    // ---- step-invariant VGPR fragments: Whh (all gates) + Wih gates 2,3 ----
    short8 whf[4][4];   // Whh
    short8 wfv[2][4];   // Wih gates g,o
    float bs[4];
    #pragma unroll
    for (int g = 0; g < 4; ++g) {
        const int j = g * 128 + w * 16 + c;
        bs[g] = bih[j] + bhh[j];
        const float* ph = Whh + (long)j * HDIM + q * 8;
        #pragma unroll
        for (int ks = 0; ks < 4; ++ks) {
            float4 b0 = *(const float4*)(ph + ks * 32);
            float4 b1 = *(const float4*)(ph + ks * 32 + 4);
            short8 u;
            u[0] = (short)f2bf(b0.x); u[1] = (short)f2bf(b0.y);
            u[2] = (short)f2bf(b0.z); u[3] = (short)f2bf(b0.w);
            u[4] = (short)f2bf(b1.x); u[5] = (short)f2bf(b1.y);
            u[6] = (short)f2bf(b1.z); u[7] = (short)f2bf(b1.w);
            whf[g][ks] = u;
        }
    }
    #pragma unroll
    for (int gi = 0; gi < 2; ++gi) {
        const int j = (2 + gi) * 128 + w * 16 + c;
        const float* pi = Wih + (long)j * EDIM + q * 8;
        #pragma unroll
        for (int ks = 0; ks < 4; ++ks) {
            float4 a0 = *(const float4*)(pi + ks * 32);
            float4 a1 = *(const float4*)(pi + ks * 32 + 4);
            short8 s;
            s[0] = (short)f2bf(a0.x); s[1] = (short)f2bf(a0.y);
            s[2] = (short)f2bf(a0.z); s[3] = (short)f2bf(a0.w);
            s[4] = (short)f2bf(a1.x); s[5] = (short)f2bf(a1.y);
            s[6] = (short)f2bf(a1.z); s[7] = (short)f2bf(a1.w);
            wfv[gi][ks] = s;
        }
    }

    // staging geometry: thread covers 8B of the 16x128 x-tile
    const int srow = tid >> 5, squad = tid & 31;
    const int sdst = ((squad >> 1) * 16 + srow) * 8 + (squad & 1) * 4;
    // kb-subtile write slot for h (row filled per r below)
    const int hkb = w * 2 + (c >> 3), hsub = c & 7;

    for (int half = 0; half < 2; ++half) {
        // balanced pairing: block b runs sorted chunk b then chunk 511-b
        const int cid = half ? (NCHUNK - 1 - (int)blockIdx.x) : (int)blockIdx.x;
        const int r0 = cid * 16;
        if (tid < 16) { int p = perm[r0 + tid]; pemb[tid] = p; lenb[tid] = lens[p]; }
        { s16x4 z = {0, 0, 0, 0}; *(s16x4*)&hb2[0][tid * 4] = z; }  // h(0)=0 (2048 shorts)
        const unsigned short* xsrc = &xt[(long)(r0 + srow) * EDIM + squad * 4];
        { s16x4 v = *(const s16x4*)xsrc; *(s16x4*)&xb2[0][sdst] = v; }  // x(t=0)
        __syncthreads();

        const int steps = lenb[15];           // rows sorted ascending in chunk
        int lenr[4];
        #pragma unroll
        for (int r = 0; r < 4; ++r) lenr[r] = lenb[q * 4 + r];

        float c_reg[4] = {0.f, 0.f, 0.f, 0.f};
        float h_reg[4] = {0.f, 0.f, 0.f, 0.f};

        int cur = 0;
        const unsigned short* xp = xsrc;      // plane-t pointer; +XSLAB = t+1
        for (int t = 0; t < steps; ++t) {
            // prefetch x(t+1): pointer walk, no per-step 64-bit mads.
            // At t=steps-1 (steps=32) this reads plane 32 = start of h_last
            // region (mapped ws); the staged value is never consumed.
            xp += XSLAB;
            s16x4 xg = *(const s16x4*)xp;

            f32x4 acc[4];
            #pragma unroll
            for (int g = 0; g < 4; ++g) {     // bias pre-loaded into accumulator
                f32x4 a = {bs[g], bs[g], bs[g], bs[g]};
                acc[g] = a;
            }
            if (t) {                          // recurrent part (h(0)=0: skip)
                #pragma unroll
                for (int ks = 0; ks < 4; ++ks) {
                    short8 ha = *(const short8*)&hb2[cur][((q + 4 * ks) * 16 + c) * 8];
                    #pragma unroll
                    for (int g = 0; g < 4; ++g)
                        acc[g] = __builtin_amdgcn_mfma_f32_16x16x32_bf16(ha, whf[g][ks], acc[g], 0, 0, 0);
                }
            }
            #pragma unroll
            for (int ks = 0; ks < 4; ++ks) {  // input part
                short8 xa = *(const short8*)&xb2[cur][((q + 4 * ks) * 16 + c) * 8];
                short8 b0 = *(const short8*)&wih2[((q + 4 * ks) * 256 + w * 16 + c) * 8];
                short8 b1 = *(const short8*)&wih2[((q + 4 * ks) * 256 + 128 + w * 16 + c) * 8];
                acc[0] = __builtin_amdgcn_mfma_f32_16x16x32_bf16(xa, b0, acc[0], 0, 0, 0);
                acc[1] = __builtin_amdgcn_mfma_f32_16x16x32_bf16(xa, b1, acc[1], 0, 0, 0);
                acc[2] = __builtin_amdgcn_mfma_f32_16x16x32_bf16(xa, wfv[0][ks], acc[2], 0, 0, 0);
                acc[3] = __builtin_amdgcn_mfma_f32_16x16x32_bf16(xa, wfv[1][ks], acc[3], 0, 0, 0);
            }
            const int nxt = cur ^ 1;
            // write next-step x tile (vmcnt for xg drains here, post-MFMA)
            *(s16x4*)&xb2[nxt][sdst] = xg;

            #pragma unroll
            for (int r = 0; r < 4; ++r) {     // acc[g][r]: row q*4+r, gate g
                float cn = sigmoid_f(acc[1][r]) * c_reg[r]
                         + sigmoid_f(acc[0][r]) * tanh_f(acc[2][r]);
                float hn = sigmoid_f(acc[3][r]) * tanh_f(cn);
                if (t < lenr[r]) { c_reg[r] = cn; h_reg[r] = hn; }
                const int row = q * 4 + r;
                hb2[nxt][(hkb * 16 + row) * 8 + hsub] = f2bf(h_reg[r]);
            }
            __syncthreads();                  // single barrier per step (dbuf)
            cur = nxt;
        }
        #pragma unroll
        for (int r = 0; r < 4; ++r)
            h_last[(long)pemb[q * 4 + r] * HDIM + w * 16 + c] = h_reg[r];
        if (half == 0) __syncthreads();       // pemb/lenb/hb/xb reused by 2nd chunk
    }
}

// ---------------- K3: segmented softmax attention + output GEMMs (fp32 out) -
__global__ __launch_bounds__(64) void k3_attn(
    const float* __restrict__ h_last, const int* __restrict__ seg,
    const float* __restrict__ attn, const float* __restrict__ Wout,
    const float* __restrict__ Wcls, float* __restrict__ out)
{
    __shared__ float code_s[128];
    const int g = blockIdx.x, l = threadIdx.x;

    int lo, hi;
    { int a = 0, b = NPATH; while (a < b) { int m = (a + b) >> 1; if (seg[m] < g) a = m + 1; else b = m; } lo = a; }
    { int a = lo, b = NPATH; while (a < b) { int m = (a + b) >> 1; if (seg[m] < g + 1) a = m + 1; else b = m; } hi = a; }

    float a0 = attn[l], a1 = attn[l + 64];
    float mrun = -1e30f, Z = 0.f;
    for (int n = lo; n < hi; ++n) {        // online softmax stats
        const float* hr = &h_last[(long)n * HDIM];
        float v = hr[l] * a0 + hr[l + 64] * a1;
        #pragma unroll
        for (int m = 1; m < 64; m <<= 1) v += __shfl_xor(v, m, 64);
        float nm = fmaxf(mrun, v);
        Z = Z * __expf(mrun - nm) + __expf(v - nm);
        mrun = nm;
    }
    float w0 = 0.f, w1 = 0.f;
    for (int n = lo; n < hi; ++n) {        // weighted sum
        const float* hr = &h_last[(long)n * HDIM];
        float v = hr[l] * a0 + hr[l + 64] * a1;
        #pragma unroll
        for (int m = 1; m < 64; m <<= 1) v += __shfl_xor(v, m, 64);
        float at = __expf(v - mrun) / Z;
        w0 += at * hr[l]; w1 += at * hr[l + 64];
    }
    float inv_cnt = (hi > lo) ? 1.f / (float)(hi - lo) : 0.f;
    code_s[l] = w0 * inv_cnt; code_s[l + 64] = w1 * inv_cnt;
    __syncthreads();

    float cv0 = 0.f, cv1 = 0.f;            // code @ W_out.T
    for (int k = 0; k < 128; ++k) {
        float ck = code_s[k];
        cv0 += ck * Wout[l * 128 + k];
        cv1 += ck * Wout[(l + 64) * 128 + k];
    }
    out[2048 + g * 128 + l]      = cv0;
    out[2048 + g * 128 + l + 64] = cv1;

    float p0 = cv0 * Wcls[l] + cv1 * Wcls[l + 64];          // cv @ W_cls.T
    float p1 = cv0 * Wcls[128 + l] + cv1 * Wcls[128 + l + 64];
    #pragma unroll
    for (int m = 1; m < 64; m <<= 1) { p0 += __shfl_xor(p0, m, 64); p1 += __shfl_xor(p1, m, 64); }
    if (l == 0) { out[g * 2 + 0] = p0; out[g * 2 + 1] = p1; }
    if (g == 0) { out[133120 + l] = attn[l]; out[133120 + 64 + l] = attn[l + 64]; }
}

extern "C" void kernel_launch(void* const* d_in, const int* in_sizes, int n_in,
                              void* d_out, int out_size, void* d_ws, size_t ws_size,
                              hipStream_t stream) {
    const float* inp  = (const float*)d_in[0];
    const int*   lens = (const int*)d_in[1];
    const int*   seg  = (const int*)d_in[2];
    const float* Win  = (const float*)d_in[3];
    const float* gam  = (const float*)d_in[4];
    const float* bet  = (const float*)d_in[5];
    const float* Wih  = (const float*)d_in[6];
    const float* Whh  = (const float*)d_in[7];
    const float* bih  = (const float*)d_in[8];
    const float* bhh  = (const float*)d_in[9];
    const float* attn = (const float*)d_in[10];
    const float* Wout = (const float*)d_in[11];
    const float* Wcls = (const float*)d_in[12];

    unsigned short* xt = (unsigned short*)d_ws;                               // 64 MB bf16 x~ [t][slot][E]
    float* h_last = (float*)((char*)d_ws + (size_t)NTOK * EDIM * 2);          // 4 MB f32
    int* perm = (int*)((char*)d_ws + (size_t)NTOK * EDIM * 2
                                   + (size_t)NPATH * HDIM * 4);               // 32 KB
    int* inv  = perm + NPATH;                                                 // 32 KB

    hipLaunchKernelGGL(k0_sort, dim3(1), dim3(512), 0, stream, lens, perm, inv);
    hipLaunchKernelGGL(k1_proj, dim3(256), dim3(512), 0, stream, inp, Win, gam, bet, inv, xt);
    hipLaunchKernelGGL(k2_lstm, dim3(NCHUNK / 2), dim3(512), 0, stream,
                       xt, Wih, Whh, bih, bhh, lens, perm, h_last);
    hipLaunchKernelGGL(k3_attn, dim3(NGRP), dim3(64), 0, stream, h_last, seg, attn, Wout, Wcls,
                       (float*)d_out);
}